// Round 1
// baseline (17597.906 us; speedup 1.0000x reference)
//
#include <hip/hip_runtime.h>
#include <hip/hip_bf16.h>
#include <math.h>

// Problem constants (from reference setup_inputs)
#define BB 4
#define SS 1024
#define DD 768
#define HH 12
#define LL 6
#define FF 3072
#define VV 32000
#define DK 64
#define MM (BB * SS)   // 4096 rows

// ---------------------------------------------------------------------------
// Embedding + sinusoidal positional encoding
// x[b*S+s, d] = emb[tokens[b*S+s], d] + PE(s, d)
__global__ void embed_kernel(const int* __restrict__ tokens,
                             const float* __restrict__ emb,
                             float* __restrict__ x) {
    const int row = blockIdx.x;          // b*S + s
    const int s = row % SS;
    const int tok = tokens[row];
    const float* er = emb + (size_t)tok * DD;
    float* xr = x + (size_t)row * DD;
    const float neg_ln_base = -logf(10000.0f) / (float)DD;
    for (int d = threadIdx.x; d < DD; d += blockDim.x) {
        int i2 = d & ~1;                 // 2*i
        float div = expf((float)i2 * neg_ln_base);
        float ang = (float)s * div;
        float pe = (d & 1) ? cosf(ang) : sinf(ang);
        xr[d] = er[d] + pe;
    }
}

// ---------------------------------------------------------------------------
// LayerNorm: one 256-thread block per row of D=768
__global__ __launch_bounds__(256) void ln_kernel(const float* __restrict__ x,
                                                 const float* __restrict__ g,
                                                 const float* __restrict__ b,
                                                 float* __restrict__ out) {
    const int row = blockIdx.x;
    const float* xr = x + (size_t)row * DD;
    float s = 0.f, s2 = 0.f;
    for (int d = threadIdx.x; d < DD; d += blockDim.x) {
        float v = xr[d];
        s += v; s2 += v * v;
    }
    __shared__ float rs[4], rs2[4];
    for (int off = 32; off; off >>= 1) {
        s  += __shfl_down(s, off);
        s2 += __shfl_down(s2, off);
    }
    const int wid = threadIdx.x >> 6;
    if ((threadIdx.x & 63) == 0) { rs[wid] = s; rs2[wid] = s2; }
    __syncthreads();
    s  = rs[0] + rs[1] + rs[2] + rs[3];
    s2 = rs2[0] + rs2[1] + rs2[2] + rs2[3];
    const float mu = s / (float)DD;
    const float var = s2 / (float)DD - mu * mu;
    const float r = rsqrtf(var + 1e-5f);
    float* orow = out + (size_t)row * DD;
    for (int d = threadIdx.x; d < DD; d += blockDim.x)
        orow[d] = (xr[d] - mu) * r * g[d] + b[d];
}

// ---------------------------------------------------------------------------
// Generic fp32 GEMM: C[M,N] = act(A[M,K] @ B + bias) (+ res)
// BTRANS=0: B is [K,N] row-major (weights). BTRANS=1: B is [N,K] row-major (head_W).
// ACT=1: exact GELU. RES=1: add res[M,N] elementwise.
// Tile 64x64, BK=16, 256 threads, 4x4 per thread. All dims must divide tiles.
template <int BTRANS, int ACT, int RES>
__global__ __launch_bounds__(256) void gemm_kernel(const float* __restrict__ A,
                                                   const float* __restrict__ Bm,
                                                   const float* __restrict__ bias,
                                                   const float* __restrict__ res,
                                                   float* __restrict__ C,
                                                   int M, int N, int K) {
    __shared__ float As[16][65];
    __shared__ float Bs[16][65];
    const int bm = blockIdx.y * 64;
    const int bn = blockIdx.x * 64;
    const int tid = threadIdx.x;
    const int tx = tid & 15;
    const int ty = tid >> 4;
    const int ar = tid >> 2;          // 0..63
    const int ac = (tid & 3) * 4;     // 0,4,8,12
    const int br = tid >> 4;          // 0..15
    const int bc = (tid & 15) * 4;    // 0..60

    float acc[4][4] = {};

    for (int k0 = 0; k0 < K; k0 += 16) {
        float4 av = *(const float4*)(A + (size_t)(bm + ar) * K + k0 + ac);
        As[ac + 0][ar] = av.x;
        As[ac + 1][ar] = av.y;
        As[ac + 2][ar] = av.z;
        As[ac + 3][ar] = av.w;
        if (BTRANS) {
            float4 bv = *(const float4*)(Bm + (size_t)(bn + ar) * K + k0 + ac);
            Bs[ac + 0][ar] = bv.x;
            Bs[ac + 1][ar] = bv.y;
            Bs[ac + 2][ar] = bv.z;
            Bs[ac + 3][ar] = bv.w;
        } else {
            float4 bv = *(const float4*)(Bm + (size_t)(k0 + br) * N + bn + bc);
            Bs[br][bc + 0] = bv.x;
            Bs[br][bc + 1] = bv.y;
            Bs[br][bc + 2] = bv.z;
            Bs[br][bc + 3] = bv.w;
        }
        __syncthreads();
        #pragma unroll
        for (int kk = 0; kk < 16; kk++) {
            float a[4], bb[4];
            #pragma unroll
            for (int i = 0; i < 4; i++) a[i] = As[kk][ty * 4 + i];
            #pragma unroll
            for (int j = 0; j < 4; j++) bb[j] = Bs[kk][tx * 4 + j];
            #pragma unroll
            for (int i = 0; i < 4; i++)
                #pragma unroll
                for (int j = 0; j < 4; j++)
                    acc[i][j] += a[i] * bb[j];
        }
        __syncthreads();
    }

    #pragma unroll
    for (int i = 0; i < 4; i++) {
        const int m = bm + ty * 4 + i;
        #pragma unroll
        for (int j = 0; j < 4; j++) {
            const int n = bn + tx * 4 + j;
            float v = acc[i][j];
            if (bias) v += bias[n];
            if (ACT == 1) v = 0.5f * v * (1.0f + erff(v * 0.70710678118654752f));
            if (RES) v += res[(size_t)m * N + n];
            C[(size_t)m * N + n] = v;
        }
    }
}

// ---------------------------------------------------------------------------
// Causal attention, one wave (64 lanes) per (b, h, q-row).
// q,k,v are [B*S, D] with head h at columns [h*64, h*64+64).
__global__ __launch_bounds__(64) void attn_kernel(const float* __restrict__ q,
                                                  const float* __restrict__ k,
                                                  const float* __restrict__ v,
                                                  float* __restrict__ o) {
    const int bid = blockIdx.x;           // ((b*H + h)*S + s)
    const int s = bid % SS;
    const int bh = bid / SS;
    const int h = bh % HH;
    const int b = bh / HH;
    const int lane = threadIdx.x;
    const float scale = 0.125f;           // 1/sqrt(64)

    __shared__ float sc[SS];
    __shared__ float qv[DK];

    const float* qp = q + ((size_t)(b * SS + s)) * DD + h * DK;
    qv[lane] = qp[lane];                  // blockDim==64==DK
    __syncthreads();

    // scores for keys 0..s
    for (int kk = lane; kk <= s; kk += 64) {
        const float* kp = k + ((size_t)(b * SS + kk)) * DD + h * DK;
        float dot = 0.f;
        #pragma unroll 8
        for (int d = 0; d < DK; d++) dot += qv[d] * kp[d];
        sc[kk] = dot * scale;
    }
    __syncthreads();

    // softmax over sc[0..s]
    float m = -3.0e38f;
    for (int kk = lane; kk <= s; kk += 64) m = fmaxf(m, sc[kk]);
    for (int off = 32; off; off >>= 1) m = fmaxf(m, __shfl_down(m, off));
    m = __shfl(m, 0);
    float sum = 0.f;
    for (int kk = lane; kk <= s; kk += 64) {
        float e = expf(sc[kk] - m);
        sc[kk] = e;
        sum += e;
    }
    for (int off = 32; off; off >>= 1) sum += __shfl_down(sum, off);
    sum = __shfl(sum, 0);
    __syncthreads();
    const float inv = 1.0f / sum;

    // PV: lane owns output dim d = lane
    float acc = 0.f;
    for (int kk = 0; kk <= s; kk++) {
        acc += sc[kk] * v[((size_t)(b * SS + kk)) * DD + h * DK + lane];
    }
    o[((size_t)(b * SS + s)) * DD + h * DK + lane] = acc * inv;
}

// ---------------------------------------------------------------------------
extern "C" void kernel_launch(void* const* d_in, const int* in_sizes, int n_in,
                              void* d_out, int out_size, void* d_ws, size_t ws_size,
                              hipStream_t stream) {
    const int*   tokens = (const int*)d_in[0];
    const float* emb    = (const float*)d_in[1];
    const float* Wq     = (const float*)d_in[2];
    const float* bq     = (const float*)d_in[3];
    const float* Wk     = (const float*)d_in[4];
    const float* bk     = (const float*)d_in[5];
    const float* Wv     = (const float*)d_in[6];
    const float* bv     = (const float*)d_in[7];
    const float* Wo     = (const float*)d_in[8];
    const float* bo     = (const float*)d_in[9];
    const float* W1     = (const float*)d_in[10];
    const float* b1     = (const float*)d_in[11];
    const float* W2     = (const float*)d_in[12];
    const float* b2     = (const float*)d_in[13];
    const float* ln1_g  = (const float*)d_in[14];
    const float* ln1_b  = (const float*)d_in[15];
    const float* ln2_g  = (const float*)d_in[16];
    const float* ln2_b  = (const float*)d_in[17];
    const float* lnf_g  = (const float*)d_in[18];
    const float* lnf_b  = (const float*)d_in[19];
    const float* headW  = (const float*)d_in[20];
    float* out = (float*)d_out;

    // workspace layout (floats)
    const size_t MD = (size_t)MM * DD;       // 3,145,728
    const size_t MF = (size_t)MM * FF;       // 12,582,912
    float* ws  = (float*)d_ws;
    float* x   = ws;                 // [M, D]
    float* h   = ws + MD;            // [M, D]
    float* q   = ws + 2 * MD;        // [M, D]
    float* kbuf= ws + 3 * MD;        // [M, D]
    float* vbuf= ws + 4 * MD;        // [M, D]
    float* ao  = ws + 5 * MD;        // [M, D]
    float* mid = ws + 6 * MD;        // [M, F]
    (void)ws_size; (void)in_sizes; (void)n_in; (void)out_size;

    embed_kernel<<<MM, 256, 0, stream>>>(tokens, emb, x);

    const dim3 gD(DD / 64, MM / 64);   // GEMMs with N=D
    const dim3 gF(FF / 64, MM / 64);   // GEMM with N=F
    const dim3 gV(VV / 64, MM / 64);   // head GEMM

    for (int l = 0; l < LL; l++) {
        const float* wq = Wq + (size_t)l * DD * DD;
        const float* wk = Wk + (size_t)l * DD * DD;
        const float* wv = Wv + (size_t)l * DD * DD;
        const float* wo = Wo + (size_t)l * DD * DD;
        const float* w1 = W1 + (size_t)l * DD * FF;
        const float* w2 = W2 + (size_t)l * FF * DD;

        ln_kernel<<<MM, 256, 0, stream>>>(x, ln1_g + l * DD, ln1_b + l * DD, h);
        gemm_kernel<0, 0, 0><<<gD, 256, 0, stream>>>(h, wq, bq + l * DD, nullptr, q,    MM, DD, DD);
        gemm_kernel<0, 0, 0><<<gD, 256, 0, stream>>>(h, wk, bk + l * DD, nullptr, kbuf, MM, DD, DD);
        gemm_kernel<0, 0, 0><<<gD, 256, 0, stream>>>(h, wv, bv + l * DD, nullptr, vbuf, MM, DD, DD);
        attn_kernel<<<BB * HH * SS, 64, 0, stream>>>(q, kbuf, vbuf, ao);
        gemm_kernel<0, 0, 1><<<gD, 256, 0, stream>>>(ao, wo, bo + l * DD, x, x, MM, DD, DD);
        ln_kernel<<<MM, 256, 0, stream>>>(x, ln2_g + l * DD, ln2_b + l * DD, h);
        gemm_kernel<0, 1, 0><<<gF, 256, 0, stream>>>(h, w1, b1 + l * FF, nullptr, mid, MM, FF, DD);
        gemm_kernel<0, 0, 1><<<gD, 256, 0, stream>>>(mid, w2, b2 + l * DD, x, x, MM, DD, FF);
    }

    ln_kernel<<<MM, 256, 0, stream>>>(x, lnf_g, lnf_b, h);
    gemm_kernel<1, 0, 0><<<gV, 256, 0, stream>>>(h, headW, nullptr, nullptr, out, MM, VV, DD);
}

// Round 2
// 4770.521 us; speedup vs baseline: 3.6889x; 3.6889x over previous
//
#include <hip/hip_runtime.h>
#include <hip/hip_bf16.h>
#include <math.h>

// Problem constants
#define BB 4
#define SS 1024
#define DD 768
#define HH 12
#define LL 6
#define FF 3072
#define VV 32000
#define DK 64
#define MM (BB * SS)   // 4096 rows

typedef __attribute__((ext_vector_type(8))) short s8v;   // 8 bf16 (4 VGPRs)
typedef __attribute__((ext_vector_type(4))) float f4v;   // 4 fp32 acc

__device__ inline unsigned short f2bf_bits(float f) {
    unsigned u = __builtin_bit_cast(unsigned, f);
    unsigned r = (u + 0x7fffu + ((u >> 16) & 1u)) >> 16;
    return (unsigned short)r;
}

__device__ inline void gl_lds16(const void* g, void* l) {
    __builtin_amdgcn_global_load_lds((const __attribute__((address_space(1))) void*)g,
                                     (__attribute__((address_space(3))) void*)l, 16, 0, 0);
}

// ---------------------------------------------------------------------------
// Embedding + sinusoidal positional encoding (fp32 out)
__global__ void embed_kernel(const int* __restrict__ tokens,
                             const float* __restrict__ emb,
                             float* __restrict__ x) {
    const int row = blockIdx.x;
    const int s = row % SS;
    const int tok = tokens[row];
    const float* er = emb + (size_t)tok * DD;
    float* xr = x + (size_t)row * DD;
    const float neg_ln_base = -logf(10000.0f) / (float)DD;
    for (int d = threadIdx.x; d < DD; d += blockDim.x) {
        int i2 = d & ~1;
        float div = expf((float)i2 * neg_ln_base);
        float ang = (float)s * div;
        float pe = (d & 1) ? cosf(ang) : sinf(ang);
        xr[d] = er[d] + pe;
    }
}

// ---------------------------------------------------------------------------
// LayerNorm: one 256-thread block per row. OUTBF=1 -> bf16 output bits.
template <int OUTBF>
__global__ __launch_bounds__(256) void ln_kernel(const float* __restrict__ x,
                                                 const float* __restrict__ g,
                                                 const float* __restrict__ b,
                                                 void* __restrict__ outp) {
    const int row = blockIdx.x;
    const float* xr = x + (size_t)row * DD;
    float s = 0.f, s2 = 0.f;
    for (int d = threadIdx.x; d < DD; d += blockDim.x) {
        float v = xr[d];
        s += v; s2 += v * v;
    }
    __shared__ float rs[4], rs2[4];
    for (int off = 32; off; off >>= 1) {
        s  += __shfl_down(s, off);
        s2 += __shfl_down(s2, off);
    }
    const int wid = threadIdx.x >> 6;
    if ((threadIdx.x & 63) == 0) { rs[wid] = s; rs2[wid] = s2; }
    __syncthreads();
    s  = rs[0] + rs[1] + rs[2] + rs[3];
    s2 = rs2[0] + rs2[1] + rs2[2] + rs2[3];
    const float mu = s / (float)DD;
    const float var = s2 / (float)DD - mu * mu;
    const float r = rsqrtf(var + 1e-5f);
    for (int d = threadIdx.x; d < DD; d += blockDim.x) {
        float v = (xr[d] - mu) * r * g[d] + b[d];
        if (OUTBF) ((unsigned short*)outp)[(size_t)row * DD + d] = f2bf_bits(v);
        else       ((float*)outp)[(size_t)row * DD + d] = v;
    }
}

// ---------------------------------------------------------------------------
// Transpose+convert: fp32 in[R,C] -> bf16 out[C,R]
__global__ __launch_bounds__(256) void tconv_kernel(const float* __restrict__ in,
                                                    unsigned short* __restrict__ out,
                                                    int R, int C) {
    __shared__ float t[64][65];
    const int r0 = blockIdx.y * 64, c0 = blockIdx.x * 64;
    const int tid = threadIdx.x;
    const int lr = tid >> 6;   // 0..3
    const int lc = tid & 63;
    #pragma unroll
    for (int it = 0; it < 16; ++it) {
        int r = it * 4 + lr;
        t[r][lc] = in[(size_t)(r0 + r) * C + c0 + lc];
    }
    __syncthreads();
    #pragma unroll
    for (int it = 0; it < 16; ++it) {
        int c = it * 4 + lr;
        out[(size_t)(c0 + c) * R + r0 + lc] = f2bf_bits(t[lc][c]);
    }
}

// Straight convert fp32 -> bf16, 4 elems/thread (n divisible by 1024)
__global__ __launch_bounds__(256) void conv_kernel(const float* __restrict__ in,
                                                   unsigned short* __restrict__ out,
                                                   long n4) {
    long i = (long)blockIdx.x * 256 + threadIdx.x;
    if (i < n4) {
        float4 v = ((const float4*)in)[i];
        ushort4 o;
        o.x = f2bf_bits(v.x); o.y = f2bf_bits(v.y);
        o.z = f2bf_bits(v.z); o.w = f2bf_bits(v.w);
        ((ushort4*)out)[i] = o;
    }
}

// k [B*S, D] fp32 -> kt [B,H,DK,S] fp32
__global__ __launch_bounds__(256) void ktrans_kernel(const float* __restrict__ k,
                                                     float* __restrict__ kt) {
    const int bh = blockIdx.y;
    const int b = bh / HH, h = bh % HH;
    const int s0 = blockIdx.x * 64;
    __shared__ float t[64][65];
    const int tid = threadIdx.x;
    const int lr = tid >> 6;
    const int lc = tid & 63;
    #pragma unroll
    for (int it = 0; it < 16; ++it) {
        int s = it * 4 + lr;
        t[s][lc] = k[(size_t)(b * SS + s0 + s) * DD + h * DK + lc];
    }
    __syncthreads();
    #pragma unroll
    for (int it = 0; it < 16; ++it) {
        int d = it * 4 + lr;
        kt[((size_t)(b * HH + h) * DK + d) * SS + s0 + lc] = t[lc][d];
    }
}

// ---------------------------------------------------------------------------
// bf16 MFMA GEMM (m97 structure): C[M,N] = act(A[M,K] @ Bt[N,K]^T + bias) (+res)
// 128x128 tile, BK=32, 256 threads = 4 waves (2x2), each wave 64x64 = 4x4 frags.
template <int ACT, int RES, int OUTBF>
__global__ __launch_bounds__(256) void gemm_mfma(const unsigned short* __restrict__ A,
                                                 const unsigned short* __restrict__ Bt,
                                                 const float* __restrict__ bias,
                                                 const float* res,
                                                 void* Cout, int M, int N, int K) {
    __shared__ unsigned short As[128 * 32];
    __shared__ unsigned short Bs[128 * 32];
    const int tid = threadIdx.x;
    const int bm = blockIdx.y * 128, bn = blockIdx.x * 128;
    const int lane = tid & 63;
    const int wave = tid >> 6;
    const int wm = (wave >> 1) * 64, wn = (wave & 1) * 64;

    f4v acc[4][4];
    #pragma unroll
    for (int i = 0; i < 4; i++)
        #pragma unroll
        for (int j = 0; j < 4; j++)
            acc[i][j] = (f4v){0.f, 0.f, 0.f, 0.f};

    // staging: thread t loads 8 bf16 (16B) of row (t>>2), k-chunk (t&3)*8; two 64-row halves
    const int arow = tid >> 2;
    const int acol = (tid & 3) * 8;
    const unsigned short* gA0 = A  + (size_t)(bm + arow) * K + acol;
    const unsigned short* gA1 = gA0 + (size_t)64 * K;
    const unsigned short* gB0 = Bt + (size_t)(bn + arow) * K + acol;
    const unsigned short* gB1 = gB0 + (size_t)64 * K;
    char* lA0 = (char*)As + tid * 16;
    char* lA1 = lA0 + 4096;
    char* lB0 = (char*)Bs + tid * 16;
    char* lB1 = lB0 + 4096;

    const int fr = lane & 15;          // frag row/col within 16
    const int fk = (lane >> 4) * 8;    // frag k offset

    for (int k0 = 0; k0 < K; k0 += 32) {
        gl_lds16(gA0 + k0, lA0);
        gl_lds16(gA1 + k0, lA1);
        gl_lds16(gB0 + k0, lB0);
        gl_lds16(gB1 + k0, lB1);
        __syncthreads();
        s8v af[4], bf[4];
        #pragma unroll
        for (int i = 0; i < 4; i++)
            af[i] = *(const s8v*)(As + (wm + i * 16 + fr) * 32 + fk);
        #pragma unroll
        for (int j = 0; j < 4; j++)
            bf[j] = *(const s8v*)(Bs + (wn + j * 16 + fr) * 32 + fk);
        #pragma unroll
        for (int i = 0; i < 4; i++)
            #pragma unroll
            for (int j = 0; j < 4; j++)
                acc[i][j] = __builtin_amdgcn_mfma_f32_16x16x32_bf16(af[i], bf[j], acc[i][j], 0, 0, 0);
        __syncthreads();
    }

    // epilogue: C/D layout col=lane&15, row=(lane>>4)*4+reg
    const int r0 = bm + wm + (lane >> 4) * 4;
    const int c0 = bn + wn + fr;
    #pragma unroll
    for (int i = 0; i < 4; i++) {
        #pragma unroll
        for (int j = 0; j < 4; j++) {
            const int c = c0 + j * 16;
            const float bv = bias ? bias[c] : 0.f;
            #pragma unroll
            for (int q = 0; q < 4; q++) {
                const int r = r0 + i * 16 + q;
                float v = acc[i][j][q] + bv;
                if (ACT) v = 0.5f * v * (1.0f + erff(v * 0.70710678118654752f));
                if (RES) v += res[(size_t)r * N + c];
                if (OUTBF) ((unsigned short*)Cout)[(size_t)r * N + c] = f2bf_bits(v);
                else       ((float*)Cout)[(size_t)r * N + c] = v;
            }
        }
    }
}

// ---------------------------------------------------------------------------
// Causal attention, one wave per (b,h,q-row). kt is [B,H,DK,S] fp32 (coalesced QK).
__global__ __launch_bounds__(64) void attn_kernel(const float* __restrict__ q,
                                                  const float* __restrict__ kt,
                                                  const float* __restrict__ v,
                                                  unsigned short* __restrict__ o) {
    const int bid = blockIdx.x;           // ((b*H + h)*S + s)
    const int s = bid % SS;
    const int bh = bid / SS;
    const int h = bh % HH;
    const int b = bh / HH;
    const int lane = threadIdx.x;
    const float scale = 0.125f;

    __shared__ float sc[SS];
    __shared__ float qv[DK];

    qv[lane] = q[((size_t)(b * SS + s)) * DD + h * DK + lane];
    __syncthreads();

    const float* ktp = kt + (size_t)(b * HH + h) * DK * SS;
    for (int kk0 = 0; kk0 <= s; kk0 += 64) {
        float dot = 0.f;
        #pragma unroll 16
        for (int d = 0; d < DK; ++d)
            dot += qv[d] * ktp[(size_t)d * SS + kk0 + lane];
        if (kk0 + lane <= s) sc[kk0 + lane] = dot * scale;
    }
    __syncthreads();

    float m = -3.0e38f;
    for (int kk = lane; kk <= s; kk += 64) m = fmaxf(m, sc[kk]);
    for (int off = 32; off; off >>= 1) m = fmaxf(m, __shfl_down(m, off));
    m = __shfl(m, 0);
    float sum = 0.f;
    for (int kk = lane; kk <= s; kk += 64) {
        float e = expf(sc[kk] - m);
        sc[kk] = e;
        sum += e;
    }
    for (int off = 32; off; off >>= 1) sum += __shfl_down(sum, off);
    sum = __shfl(sum, 0);
    __syncthreads();
    const float inv = 1.0f / sum;

    float acc = 0.f;
    for (int kk = 0; kk <= s; kk++)
        acc += sc[kk] * v[((size_t)(b * SS + kk)) * DD + h * DK + lane];
    o[((size_t)(b * SS + s)) * DD + h * DK + lane] = f2bf_bits(acc * inv);
}

// ---------------------------------------------------------------------------
extern "C" void kernel_launch(void* const* d_in, const int* in_sizes, int n_in,
                              void* d_out, int out_size, void* d_ws, size_t ws_size,
                              hipStream_t stream) {
    const int*   tokens = (const int*)d_in[0];
    const float* emb    = (const float*)d_in[1];
    const float* Wq     = (const float*)d_in[2];
    const float* bq     = (const float*)d_in[3];
    const float* Wk     = (const float*)d_in[4];
    const float* bk     = (const float*)d_in[5];
    const float* Wv     = (const float*)d_in[6];
    const float* bv     = (const float*)d_in[7];
    const float* Wo     = (const float*)d_in[8];
    const float* bo     = (const float*)d_in[9];
    const float* W1     = (const float*)d_in[10];
    const float* b1     = (const float*)d_in[11];
    const float* W2     = (const float*)d_in[12];
    const float* b2     = (const float*)d_in[13];
    const float* ln1_g  = (const float*)d_in[14];
    const float* ln1_b  = (const float*)d_in[15];
    const float* ln2_g  = (const float*)d_in[16];
    const float* ln2_b  = (const float*)d_in[17];
    const float* lnf_g  = (const float*)d_in[18];
    const float* lnf_b  = (const float*)d_in[19];
    const float* headW  = (const float*)d_in[20];
    float* out = (float*)d_out;
    (void)in_sizes; (void)n_in; (void)out_size; (void)ws_size;

    const size_t MD  = (size_t)MM * DD;      // 3,145,728
    const size_t MF  = (size_t)MM * FF;      // 12,582,912
    const size_t DxD = (size_t)DD * DD;      // 589,824
    const size_t DxF = (size_t)DD * FF;      // 2,359,296
    const size_t HWs = (size_t)VV * DD;      // 24,576,000

    char* p = (char*)d_ws;
    float* x    = (float*)p;            p += MD * 4;
    float* q    = (float*)p;            p += MD * 4;
    float* kbuf = (float*)p;            p += MD * 4;
    float* vbuf = (float*)p;            p += MD * 4;
    char*  scr  = p;                    p += MF * 2;   // union: kt (fp32 MD) | mid (bf16 MF)
    float*          kt  = (float*)scr;
    unsigned short* mid = (unsigned short*)scr;
    unsigned short* h   = (unsigned short*)p;  p += MD * 2;
    unsigned short* ao  = (unsigned short*)p;  p += MD * 2;
    unsigned short* wqT = (unsigned short*)p;  p += DxD * 2;
    unsigned short* wkT = (unsigned short*)p;  p += DxD * 2;
    unsigned short* wvT = (unsigned short*)p;  p += DxD * 2;
    unsigned short* woT = (unsigned short*)p;  p += DxD * 2;
    unsigned short* w1T = (unsigned short*)p;  p += DxF * 2;
    unsigned short* w2T = (unsigned short*)p;  p += DxF * 2;
    unsigned short* hw  = (unsigned short*)p;  p += HWs * 2;

    embed_kernel<<<MM, 256, 0, stream>>>(tokens, emb, x);
    conv_kernel<<<(int)((HWs / 4 + 255) / 256), 256, 0, stream>>>(headW, hw, (long)(HWs / 4));

    const dim3 tD(DD / 64, DD / 64);     // [D,D] transpose
    const dim3 t1(FF / 64, DD / 64);     // W1 [D,F] -> [F,D]
    const dim3 t2(DD / 64, FF / 64);     // W2 [F,D] -> [D,F]
    const dim3 gD(DD / 128, MM / 128);
    const dim3 gF(FF / 128, MM / 128);
    const dim3 gV(VV / 128, MM / 128);
    const dim3 gKT(SS / 64, BB * HH);

    for (int l = 0; l < LL; l++) {
        tconv_kernel<<<tD, 256, 0, stream>>>(Wq + l * DxD, wqT, DD, DD);
        tconv_kernel<<<tD, 256, 0, stream>>>(Wk + l * DxD, wkT, DD, DD);
        tconv_kernel<<<tD, 256, 0, stream>>>(Wv + l * DxD, wvT, DD, DD);
        tconv_kernel<<<tD, 256, 0, stream>>>(Wo + l * DxD, woT, DD, DD);
        tconv_kernel<<<t1, 256, 0, stream>>>(W1 + l * DxF, w1T, DD, FF);
        tconv_kernel<<<t2, 256, 0, stream>>>(W2 + l * DxF, w2T, FF, DD);

        ln_kernel<1><<<MM, 256, 0, stream>>>(x, ln1_g + l * DD, ln1_b + l * DD, h);
        gemm_mfma<0, 0, 0><<<gD, 256, 0, stream>>>(h, wqT, bq + l * DD, nullptr, q,    MM, DD, DD);
        gemm_mfma<0, 0, 0><<<gD, 256, 0, stream>>>(h, wkT, bk + l * DD, nullptr, kbuf, MM, DD, DD);
        gemm_mfma<0, 0, 0><<<gD, 256, 0, stream>>>(h, wvT, bv + l * DD, nullptr, vbuf, MM, DD, DD);
        ktrans_kernel<<<gKT, 256, 0, stream>>>(kbuf, kt);
        attn_kernel<<<BB * HH * SS, 64, 0, stream>>>(q, kt, vbuf, ao);
        gemm_mfma<0, 1, 0><<<gD, 256, 0, stream>>>(ao, woT, bo + l * DD, x, x, MM, DD, DD);
        ln_kernel<1><<<MM, 256, 0, stream>>>(x, ln2_g + l * DD, ln2_b + l * DD, h);
        gemm_mfma<1, 0, 1><<<gF, 256, 0, stream>>>(h, w1T, b1 + l * FF, nullptr, mid, MM, FF, DD);
        gemm_mfma<0, 1, 0><<<gD, 256, 0, stream>>>(mid, w2T, b2 + l * DD, x, x, MM, DD, FF);
    }

    ln_kernel<1><<<MM, 256, 0, stream>>>(x, lnf_g, lnf_b, h);
    gemm_mfma<0, 0, 0><<<gV, 256, 0, stream>>>(h, hw, nullptr, nullptr, out, MM, VV, DD);
}

// Round 3
// 2023.340 us; speedup vs baseline: 8.6975x; 2.3577x over previous
//
#include <hip/hip_runtime.h>
#include <hip/hip_bf16.h>
#include <math.h>

// Problem constants
#define BB 4
#define SS 1024
#define DD 768
#define HH 12
#define LL 6
#define FF 3072
#define VV 32000
#define DK 64
#define MM (BB * SS)   // 4096 rows

typedef __attribute__((ext_vector_type(8))) short s8v;   // 8 bf16 (4 VGPRs)
typedef __attribute__((ext_vector_type(4))) float f4v;   // 4 fp32 acc

__device__ inline unsigned short f2bf_bits(float f) {
    unsigned u = __builtin_bit_cast(unsigned, f);
    unsigned r = (u + 0x7fffu + ((u >> 16) & 1u)) >> 16;
    return (unsigned short)r;
}

__device__ inline void gl_lds16(const void* g, void* l) {
    __builtin_amdgcn_global_load_lds((const __attribute__((address_space(1))) void*)g,
                                     (__attribute__((address_space(3))) void*)l, 16, 0, 0);
}

// ---------------------------------------------------------------------------
__global__ void embed_kernel(const int* __restrict__ tokens,
                             const float* __restrict__ emb,
                             float* __restrict__ x) {
    const int row = blockIdx.x;
    const int s = row % SS;
    const int tok = tokens[row];
    const float* er = emb + (size_t)tok * DD;
    float* xr = x + (size_t)row * DD;
    const float neg_ln_base = -logf(10000.0f) / (float)DD;
    for (int d = threadIdx.x; d < DD; d += blockDim.x) {
        int i2 = d & ~1;
        float div = expf((float)i2 * neg_ln_base);
        float ang = (float)s * div;
        float pe = (d & 1) ? cosf(ang) : sinf(ang);
        xr[d] = er[d] + pe;
    }
}

// ---------------------------------------------------------------------------
template <int OUTBF>
__global__ __launch_bounds__(256) void ln_kernel(const float* __restrict__ x,
                                                 const float* __restrict__ g,
                                                 const float* __restrict__ b,
                                                 void* __restrict__ outp) {
    const int row = blockIdx.x;
    const float* xr = x + (size_t)row * DD;
    float s = 0.f, s2 = 0.f;
    for (int d = threadIdx.x; d < DD; d += blockDim.x) {
        float v = xr[d];
        s += v; s2 += v * v;
    }
    __shared__ float rs[4], rs2[4];
    for (int off = 32; off; off >>= 1) {
        s  += __shfl_down(s, off);
        s2 += __shfl_down(s2, off);
    }
    const int wid = threadIdx.x >> 6;
    if ((threadIdx.x & 63) == 0) { rs[wid] = s; rs2[wid] = s2; }
    __syncthreads();
    s  = rs[0] + rs[1] + rs[2] + rs[3];
    s2 = rs2[0] + rs2[1] + rs2[2] + rs2[3];
    const float mu = s / (float)DD;
    const float var = s2 / (float)DD - mu * mu;
    const float r = rsqrtf(var + 1e-5f);
    for (int d = threadIdx.x; d < DD; d += blockDim.x) {
        float v = (xr[d] - mu) * r * g[d] + b[d];
        if (OUTBF) ((unsigned short*)outp)[(size_t)row * DD + d] = f2bf_bits(v);
        else       ((float*)outp)[(size_t)row * DD + d] = v;
    }
}

// ---------------------------------------------------------------------------
// Per-layer weight prep: all transposes batched into one launch.
// 1728 tiles: [0,432) Wq/Wk/Wv -> wqkvT[2304][768]; [432,576) Wo -> woT;
// [576,1152) W1[768,3072] -> w1T[3072][768]; [1152,1728) W2[3072,768] -> w2T[768][3072]
__global__ __launch_bounds__(256) void prep_kernel(const float* __restrict__ Wq,
                                                   const float* __restrict__ Wk,
                                                   const float* __restrict__ Wv,
                                                   const float* __restrict__ Wo,
                                                   const float* __restrict__ W1,
                                                   const float* __restrict__ W2,
                                                   unsigned short* __restrict__ wqkvT,
                                                   unsigned short* __restrict__ woT,
                                                   unsigned short* __restrict__ w1T,
                                                   unsigned short* __restrict__ w2T) {
    const int id = blockIdx.x;
    const float* src; unsigned short* dst; int R, C, t;
    if (id < 432)       { int seg = id / 144; t = id % 144;
                          src = (seg == 0 ? Wq : seg == 1 ? Wk : Wv);
                          dst = wqkvT + (size_t)seg * DD * DD; R = DD; C = DD; }
    else if (id < 576)  { t = id - 576 + 144; src = Wo; dst = woT; R = DD; C = DD; }
    else if (id < 1152) { t = id - 576;  src = W1; dst = w1T; R = DD; C = FF; }
    else                { t = id - 1152; src = W2; dst = w2T; R = FF; C = DD; }
    const int tilesC = C / 64;
    const int r0 = (t / tilesC) * 64, c0 = (t % tilesC) * 64;
    __shared__ float tb[64][65];
    const int lr = threadIdx.x >> 6, lc = threadIdx.x & 63;
    #pragma unroll
    for (int it = 0; it < 16; ++it) {
        int r = it * 4 + lr;
        tb[r][lc] = src[(size_t)(r0 + r) * C + c0 + lc];
    }
    __syncthreads();
    #pragma unroll
    for (int it = 0; it < 16; ++it) {
        int c = it * 4 + lr;
        dst[(size_t)(c0 + c) * R + r0 + lc] = f2bf_bits(tb[lc][c]);
    }
}

// Straight convert fp32 -> bf16 (head weight), 4/thread
__global__ __launch_bounds__(256) void conv_kernel(const float* __restrict__ in,
                                                   unsigned short* __restrict__ out,
                                                   long n4) {
    long i = (long)blockIdx.x * 256 + threadIdx.x;
    if (i < n4) {
        float4 v = ((const float4*)in)[i];
        ushort4 o;
        o.x = f2bf_bits(v.x); o.y = f2bf_bits(v.y);
        o.z = f2bf_bits(v.z); o.w = f2bf_bits(v.w);
        ((ushort4*)out)[i] = o;
    }
}

// ---------------------------------------------------------------------------
// bf16 MFMA GEMM, m97 structure. OUTMODE: 0 fp32 [M,N]; 1 bf16 [M,N];
// 3 fused-QKV: cols [0,768)->q bf16 [M,D], [768,1536)->k bf16 [M,D],
//              [1536,2304)->vt remap [B,H,DK,S] bf16.
template <int ACT, int RES, int OUTMODE>
__global__ __launch_bounds__(256) void gemm_mfma(const unsigned short* __restrict__ A,
                                                 const unsigned short* __restrict__ Bt,
                                                 const float* __restrict__ bias,
                                                 const float* res,
                                                 void* Cout, int M, int N, int K,
                                                 const float* biasK, const float* biasV,
                                                 unsigned short* kout, unsigned short* vtout) {
    __shared__ unsigned short As[128 * 32];
    __shared__ unsigned short Bs[128 * 32];
    const int tid = threadIdx.x;
    const int bm = blockIdx.y * 128, bn = blockIdx.x * 128;
    const int lane = tid & 63;
    const int wave = tid >> 6;
    const int wm = (wave >> 1) * 64, wn = (wave & 1) * 64;

    f4v acc[4][4];
    #pragma unroll
    for (int i = 0; i < 4; i++)
        #pragma unroll
        for (int j = 0; j < 4; j++)
            acc[i][j] = (f4v){0.f, 0.f, 0.f, 0.f};

    const int arow = tid >> 2;
    const int acol = (tid & 3) * 8;
    const unsigned short* gA0 = A  + (size_t)(bm + arow) * K + acol;
    const unsigned short* gA1 = gA0 + (size_t)64 * K;
    const unsigned short* gB0 = Bt + (size_t)(bn + arow) * K + acol;
    const unsigned short* gB1 = gB0 + (size_t)64 * K;
    char* lA0 = (char*)As + tid * 16;
    char* lA1 = lA0 + 4096;
    char* lB0 = (char*)Bs + tid * 16;
    char* lB1 = lB0 + 4096;

    const int fr = lane & 15;
    const int fk = (lane >> 4) * 8;

    for (int k0 = 0; k0 < K; k0 += 32) {
        gl_lds16(gA0 + k0, lA0);
        gl_lds16(gA1 + k0, lA1);
        gl_lds16(gB0 + k0, lB0);
        gl_lds16(gB1 + k0, lB1);
        __syncthreads();
        s8v af[4], bf[4];
        #pragma unroll
        for (int i = 0; i < 4; i++)
            af[i] = *(const s8v*)(As + (wm + i * 16 + fr) * 32 + fk);
        #pragma unroll
        for (int j = 0; j < 4; j++)
            bf[j] = *(const s8v*)(Bs + (wn + j * 16 + fr) * 32 + fk);
        #pragma unroll
        for (int i = 0; i < 4; i++)
            #pragma unroll
            for (int j = 0; j < 4; j++)
                acc[i][j] = __builtin_amdgcn_mfma_f32_16x16x32_bf16(af[i], bf[j], acc[i][j], 0, 0, 0);
        __syncthreads();
    }

    const int r0 = bm + wm + (lane >> 4) * 4;
    const int c0 = bn + wn + fr;
    #pragma unroll
    for (int i = 0; i < 4; i++) {
        const int rb = r0 + i * 16;     // 4-aligned row base; rows rb..rb+3
        #pragma unroll
        for (int j = 0; j < 4; j++) {
            const int c = c0 + j * 16;
            if (OUTMODE == 3) {
                const int seg = (c >= 1536) ? 2 : (c >= 768 ? 1 : 0);
                const int cc = c - seg * 768;
                const float bb = (seg == 0 ? bias[cc] : seg == 1 ? biasK[cc] : biasV[cc]);
                if (seg < 2) {
                    unsigned short* dst = (seg == 0 ? (unsigned short*)Cout : kout);
                    #pragma unroll
                    for (int q = 0; q < 4; q++)
                        dst[(size_t)(rb + q) * DD + cc] = f2bf_bits(acc[i][j][q] + bb);
                } else {
                    const int b_ = rb / SS, s_ = rb % SS;
                    const int h_ = cc >> 6, dd = cc & 63;
                    ushort4 pk;
                    pk.x = f2bf_bits(acc[i][j][0] + bb);
                    pk.y = f2bf_bits(acc[i][j][1] + bb);
                    pk.z = f2bf_bits(acc[i][j][2] + bb);
                    pk.w = f2bf_bits(acc[i][j][3] + bb);
                    *(ushort4*)(vtout + ((size_t)(b_ * HH + h_) * DK + dd) * SS + s_) = pk;
                }
            } else {
                const float bv = bias ? bias[c] : 0.f;
                #pragma unroll
                for (int q = 0; q < 4; q++) {
                    const int r = rb + q;
                    float v = acc[i][j][q] + bv;
                    if (ACT) v = 0.5f * v * (1.0f + erff(v * 0.70710678118654752f));
                    if (RES) v += res[(size_t)r * N + c];
                    if (OUTMODE == 1) ((unsigned short*)Cout)[(size_t)r * N + c] = f2bf_bits(v);
                    else              ((float*)Cout)[(size_t)r * N + c] = v;
                }
            }
        }
    }
}

// ---------------------------------------------------------------------------
// Flash attention: block = (qtile 64 rows, b*H), 4 waves x 16 q-rows.
// q,k: bf16 [M,D]; vt: bf16 [B,H,DK,S]; o: bf16 [M,D].
__global__ __launch_bounds__(256) void fattn_kernel(const unsigned short* __restrict__ qb,
                                                    const unsigned short* __restrict__ kb,
                                                    const unsigned short* __restrict__ vt,
                                                    unsigned short* __restrict__ o) {
    __shared__ unsigned short Ks[64 * 64];
    __shared__ unsigned short Vs[64 * 64];
    __shared__ unsigned short Ps[4][16 * 64];

    const int qt = (int)gridDim.x - 1 - (int)blockIdx.x;   // heavy tiles dispatch first
    const int bh = blockIdx.y;
    const int b = bh / HH, h = bh % HH;
    const int tid = threadIdx.x;
    const int lane = tid & 63;
    const int w = tid >> 6;
    const int fr = lane & 15;
    const int g  = lane >> 4;

    const int sr = tid >> 3;                    // 0..31
    const int sc = tid & 7;
    const int scol = (sc * 8) ^ ((sr & 7) * 8); // pre-swizzled source column (elements)

    const int q0w = qt * 64 + w * 16;
    s8v qf[2];
    {
        const unsigned short* qrow = qb + (size_t)(b * SS + q0w + fr) * DD + h * DK + g * 8;
        qf[0] = *(const s8v*)(qrow);
        qf[1] = *(const s8v*)(qrow + 32);
    }

    f4v ofr[4];
    #pragma unroll
    for (int dj = 0; dj < 4; dj++) ofr[dj] = (f4v){0.f, 0.f, 0.f, 0.f};
    float mrow[4] = {-1e30f, -1e30f, -1e30f, -1e30f};
    float lrow[4] = {0.f, 0.f, 0.f, 0.f};

    unsigned short* Pw = &Ps[w][0];
    const int ktiles = qt + 1;

    for (int t = 0; t < ktiles; ++t) {
        const int k0 = t * 64;
        #pragma unroll
        for (int i = 0; i < 2; i++) {
            const int r = i * 32 + sr;          // r&7 == sr&7
            gl_lds16(kb + (size_t)(b * SS + k0 + r) * DD + h * DK + scol,
                     (char*)Ks + i * 4096 + tid * 16);
            gl_lds16(vt + ((size_t)bh * DK + r) * SS + k0 + scol,
                     (char*)Vs + i * 4096 + tid * 16);
        }
        __syncthreads();

        // QK^T -> S frags [16q x 64k]
        f4v sfr[4];
        #pragma unroll
        for (int j = 0; j < 4; j++) {
            const char* kbase = (const char*)Ks + (j * 16 + fr) * 128;
            s8v b0 = *(const s8v*)(kbase + ((g * 16)      ^ ((fr & 7) << 4)));
            s8v b1 = *(const s8v*)(kbase + ((64 + g * 16) ^ ((fr & 7) << 4)));
            f4v a = (f4v){0.f, 0.f, 0.f, 0.f};
            a = __builtin_amdgcn_mfma_f32_16x16x32_bf16(qf[0], b0, a, 0, 0, 0);
            a = __builtin_amdgcn_mfma_f32_16x16x32_bf16(qf[1], b1, a, 0, 0, 0);
            sfr[j] = a;
        }

        const bool diag = (t == ktiles - 1);
        float p[4][4];
        #pragma unroll
        for (int j = 0; j < 4; j++)
            #pragma unroll
            for (int pq = 0; pq < 4; pq++) {
                float sv = sfr[j][pq] * 0.125f;
                if (diag && (k0 + j * 16 + fr > q0w + g * 4 + pq)) sv = -1e30f;
                p[j][pq] = sv;
            }

        // row max (16-lane group reduce)
        float rmx[4];
        #pragma unroll
        for (int pq = 0; pq < 4; pq++)
            rmx[pq] = fmaxf(fmaxf(p[0][pq], p[1][pq]), fmaxf(p[2][pq], p[3][pq]));
        #pragma unroll
        for (int off = 1; off < 16; off <<= 1)
            #pragma unroll
            for (int pq = 0; pq < 4; pq++)
                rmx[pq] = fmaxf(rmx[pq], __shfl_xor(rmx[pq], off));

        float mnew[4], scf[4], rsum[4];
        #pragma unroll
        for (int pq = 0; pq < 4; pq++) {
            mnew[pq] = fmaxf(mrow[pq], rmx[pq]);
            scf[pq]  = __expf(mrow[pq] - mnew[pq]);
            rsum[pq] = 0.f;
        }
        #pragma unroll
        for (int j = 0; j < 4; j++)
            #pragma unroll
            for (int pq = 0; pq < 4; pq++) {
                float e = __expf(p[j][pq] - mnew[pq]);
                p[j][pq] = e;
                rsum[pq] += e;
            }
        #pragma unroll
        for (int off = 1; off < 16; off <<= 1)
            #pragma unroll
            for (int pq = 0; pq < 4; pq++)
                rsum[pq] += __shfl_xor(rsum[pq], off);
        #pragma unroll
        for (int pq = 0; pq < 4; pq++) {
            lrow[pq] = lrow[pq] * scf[pq] + rsum[pq];
            mrow[pq] = mnew[pq];
        }
        #pragma unroll
        for (int dj = 0; dj < 4; dj++)
            #pragma unroll
            for (int pq = 0; pq < 4; pq++)
                ofr[dj][pq] *= scf[pq];

        // P -> LDS (bf16, swizzled), wave-private
        #pragma unroll
        for (int j = 0; j < 4; j++)
            #pragma unroll
            for (int pq = 0; pq < 4; pq++) {
                const int r = g * 4 + pq;
                *(unsigned short*)((char*)Pw + r * 128 + ((j * 32 + fr * 2) ^ ((r & 7) << 4))) =
                    f2bf_bits(p[j][pq]);
            }

        // PV: O += P[16x64] @ V^T[64d x 64k]^T
        s8v pa0 = *(const s8v*)((const char*)Pw + fr * 128 + ((g * 16)       ^ ((fr & 7) << 4)));
        s8v pa1 = *(const s8v*)((const char*)Pw + fr * 128 + ((64 + g * 16)  ^ ((fr & 7) << 4)));
        #pragma unroll
        for (int dj = 0; dj < 4; dj++) {
            const char* vbase = (const char*)Vs + (dj * 16 + fr) * 128;
            s8v v0 = *(const s8v*)(vbase + ((g * 16)      ^ ((fr & 7) << 4)));
            s8v v1 = *(const s8v*)(vbase + ((64 + g * 16) ^ ((fr & 7) << 4)));
            ofr[dj] = __builtin_amdgcn_mfma_f32_16x16x32_bf16(pa0, v0, ofr[dj], 0, 0, 0);
            ofr[dj] = __builtin_amdgcn_mfma_f32_16x16x32_bf16(pa1, v1, ofr[dj], 0, 0, 0);
        }
        __syncthreads();
    }

    // epilogue
    #pragma unroll
    for (int pq = 0; pq < 4; pq++) {
        const float inv = 1.0f / lrow[pq];
        const int row_abs = q0w + g * 4 + pq;
        #pragma unroll
        for (int dj = 0; dj < 4; dj++)
            o[(size_t)(b * SS + row_abs) * DD + h * DK + dj * 16 + fr] =
                f2bf_bits(ofr[dj][pq] * inv);
    }
}

// ---------------------------------------------------------------------------
extern "C" void kernel_launch(void* const* d_in, const int* in_sizes, int n_in,
                              void* d_out, int out_size, void* d_ws, size_t ws_size,
                              hipStream_t stream) {
    const int*   tokens = (const int*)d_in[0];
    const float* emb    = (const float*)d_in[1];
    const float* Wq     = (const float*)d_in[2];
    const float* bq     = (const float*)d_in[3];
    const float* Wk     = (const float*)d_in[4];
    const float* bk     = (const float*)d_in[5];
    const float* Wv     = (const float*)d_in[6];
    const float* bv     = (const float*)d_in[7];
    const float* Wo     = (const float*)d_in[8];
    const float* bo     = (const float*)d_in[9];
    const float* W1     = (const float*)d_in[10];
    const float* b1     = (const float*)d_in[11];
    const float* W2     = (const float*)d_in[12];
    const float* b2     = (const float*)d_in[13];
    const float* ln1_g  = (const float*)d_in[14];
    const float* ln1_b  = (const float*)d_in[15];
    const float* ln2_g  = (const float*)d_in[16];
    const float* ln2_b  = (const float*)d_in[17];
    const float* lnf_g  = (const float*)d_in[18];
    const float* lnf_b  = (const float*)d_in[19];
    const float* headW  = (const float*)d_in[20];
    float* out = (float*)d_out;
    (void)in_sizes; (void)n_in; (void)out_size; (void)ws_size;

    const size_t MD  = (size_t)MM * DD;
    const size_t MF  = (size_t)MM * FF;
    const size_t DxD = (size_t)DD * DD;
    const size_t DxF = (size_t)DD * FF;
    const size_t HWs = (size_t)VV * DD;

    char* p = (char*)d_ws;
    float*          x     = (float*)p;          p += MD * 4;
    unsigned short* qb    = (unsigned short*)p; p += MD * 2;
    unsigned short* kbuf  = (unsigned short*)p; p += MD * 2;
    unsigned short* vtb   = (unsigned short*)p; p += MD * 2;
    unsigned short* ao    = (unsigned short*)p; p += MD * 2;
    unsigned short* h     = (unsigned short*)p; p += MD * 2;
    unsigned short* mid   = (unsigned short*)p; p += MF * 2;
    unsigned short* wqkvT = (unsigned short*)p; p += 3 * DxD * 2;
    unsigned short* woT   = (unsigned short*)p; p += DxD * 2;
    unsigned short* w1T   = (unsigned short*)p; p += DxF * 2;
    unsigned short* w2T   = (unsigned short*)p; p += DxF * 2;
    unsigned short* hw    = (unsigned short*)p; p += HWs * 2;

    embed_kernel<<<MM, 256, 0, stream>>>(tokens, emb, x);
    conv_kernel<<<(int)((HWs / 4 + 255) / 256), 256, 0, stream>>>(headW, hw, (long)(HWs / 4));

    const dim3 gQKV(2304 / 128, MM / 128);
    const dim3 gD(DD * 2 / 256, MM / 128);   // (6,32)
    const dim3 gF(FF / 128, MM / 128);
    const dim3 gV(VV / 128, MM / 128);
    const dim3 gA(SS / 64, BB * HH);

    for (int l = 0; l < LL; l++) {
        prep_kernel<<<1728, 256, 0, stream>>>(Wq + l * DxD, Wk + l * DxD, Wv + l * DxD,
                                              Wo + l * DxD, W1 + l * DxF, W2 + l * DxF,
                                              wqkvT, woT, w1T, w2T);
        ln_kernel<1><<<MM, 256, 0, stream>>>(x, ln1_g + l * DD, ln1_b + l * DD, h);
        gemm_mfma<0, 0, 3><<<gQKV, 256, 0, stream>>>(h, wqkvT, bq + l * DD, nullptr, qb,
                                                     MM, 2304, DD,
                                                     bk + l * DD, bv + l * DD, kbuf, vtb);
        fattn_kernel<<<gA, 256, 0, stream>>>(qb, kbuf, vtb, ao);
        gemm_mfma<0, 1, 0><<<gD, 256, 0, stream>>>(ao, woT, bo + l * DD, x, x, MM, DD, DD,
                                                   nullptr, nullptr, nullptr, nullptr);
        ln_kernel<1><<<MM, 256, 0, stream>>>(x, ln2_g + l * DD, ln2_b + l * DD, h);
        gemm_mfma<1, 0, 1><<<gF, 256, 0, stream>>>(h, w1T, b1 + l * FF, nullptr, mid,
                                                   MM, FF, DD, nullptr, nullptr, nullptr, nullptr);
        gemm_mfma<0, 1, 0><<<gD, 256, 0, stream>>>(mid, w2T, b2 + l * DD, x, x, MM, DD, FF,
                                                   nullptr, nullptr, nullptr, nullptr);
    }

    ln_kernel<1><<<MM, 256, 0, stream>>>(x, lnf_g, lnf_b, h);
    gemm_mfma<0, 0, 0><<<gV, 256, 0, stream>>>(h, hw, nullptr, nullptr, out, MM, VV, DD,
                                               nullptr, nullptr, nullptr, nullptr);
}

// Round 4
// 1870.439 us; speedup vs baseline: 9.4084x; 1.0817x over previous
//
#include <hip/hip_runtime.h>
#include <hip/hip_bf16.h>
#include <math.h>

// Problem constants
#define BB 4
#define SS 1024
#define DD 768
#define HH 12
#define LL 6
#define FF 3072
#define VV 32000
#define DK 64
#define MM (BB * SS)   // 4096 rows

typedef __attribute__((ext_vector_type(8))) short s8v;   // 8 bf16 (4 VGPRs)
typedef __attribute__((ext_vector_type(4))) float f4v;   // 4 fp32 acc

__device__ inline unsigned short f2bf_bits(float f) {
    unsigned u = __builtin_bit_cast(unsigned, f);
    unsigned r = (u + 0x7fffu + ((u >> 16) & 1u)) >> 16;
    return (unsigned short)r;
}

__device__ inline void gl_lds16(const void* g, void* l) {
    __builtin_amdgcn_global_load_lds((const __attribute__((address_space(1))) void*)g,
                                     (__attribute__((address_space(3))) void*)l, 16, 0, 0);
}

// ---------------------------------------------------------------------------
__global__ void embed_kernel(const int* __restrict__ tokens,
                             const float* __restrict__ emb,
                             float* __restrict__ x) {
    const int row = blockIdx.x;
    const int s = row % SS;
    const int tok = tokens[row];
    const float* er = emb + (size_t)tok * DD;
    float* xr = x + (size_t)row * DD;
    const float neg_ln_base = -logf(10000.0f) / (float)DD;
    for (int d = threadIdx.x; d < DD; d += blockDim.x) {
        int i2 = d & ~1;
        float div = expf((float)i2 * neg_ln_base);
        float ang = (float)s * div;
        float pe = (d & 1) ? cosf(ang) : sinf(ang);
        xr[d] = er[d] + pe;
    }
}

// ---------------------------------------------------------------------------
template <int OUTBF>
__global__ __launch_bounds__(256) void ln_kernel(const float* __restrict__ x,
                                                 const float* __restrict__ g,
                                                 const float* __restrict__ b,
                                                 void* __restrict__ outp) {
    const int row = blockIdx.x;
    const float* xr = x + (size_t)row * DD;
    float s = 0.f, s2 = 0.f;
    for (int d = threadIdx.x; d < DD; d += blockDim.x) {
        float v = xr[d];
        s += v; s2 += v * v;
    }
    __shared__ float rs[4], rs2[4];
    for (int off = 32; off; off >>= 1) {
        s  += __shfl_down(s, off);
        s2 += __shfl_down(s2, off);
    }
    const int wid = threadIdx.x >> 6;
    if ((threadIdx.x & 63) == 0) { rs[wid] = s; rs2[wid] = s2; }
    __syncthreads();
    s  = rs[0] + rs[1] + rs[2] + rs[3];
    s2 = rs2[0] + rs2[1] + rs2[2] + rs2[3];
    const float mu = s / (float)DD;
    const float var = s2 / (float)DD - mu * mu;
    const float r = rsqrtf(var + 1e-5f);
    for (int d = threadIdx.x; d < DD; d += blockDim.x) {
        float v = (xr[d] - mu) * r * g[d] + b[d];
        if (OUTBF) ((unsigned short*)outp)[(size_t)row * DD + d] = f2bf_bits(v);
        else       ((float*)outp)[(size_t)row * DD + d] = v;
    }
}

// ---------------------------------------------------------------------------
// Per-layer weight prep (batched transposes)
__global__ __launch_bounds__(256) void prep_kernel(const float* __restrict__ Wq,
                                                   const float* __restrict__ Wk,
                                                   const float* __restrict__ Wv,
                                                   const float* __restrict__ Wo,
                                                   const float* __restrict__ W1,
                                                   const float* __restrict__ W2,
                                                   unsigned short* __restrict__ wqkvT,
                                                   unsigned short* __restrict__ woT,
                                                   unsigned short* __restrict__ w1T,
                                                   unsigned short* __restrict__ w2T) {
    const int id = blockIdx.x;
    const float* src; unsigned short* dst; int R, C, t;
    if (id < 432)       { int seg = id / 144; t = id % 144;
                          src = (seg == 0 ? Wq : seg == 1 ? Wk : Wv);
                          dst = wqkvT + (size_t)seg * DD * DD; R = DD; C = DD; }
    else if (id < 576)  { t = id - 576 + 144; src = Wo; dst = woT; R = DD; C = DD; }
    else if (id < 1152) { t = id - 576;  src = W1; dst = w1T; R = DD; C = FF; }
    else                { t = id - 1152; src = W2; dst = w2T; R = FF; C = DD; }
    const int tilesC = C / 64;
    const int r0 = (t / tilesC) * 64, c0 = (t % tilesC) * 64;
    __shared__ float tb[64][65];
    const int lr = threadIdx.x >> 6, lc = threadIdx.x & 63;
    #pragma unroll
    for (int it = 0; it < 16; ++it) {
        int r = it * 4 + lr;
        tb[r][lc] = src[(size_t)(r0 + r) * C + c0 + lc];
    }
    __syncthreads();
    #pragma unroll
    for (int it = 0; it < 16; ++it) {
        int c = it * 4 + lr;
        dst[(size_t)(c0 + c) * R + r0 + lc] = f2bf_bits(tb[lc][c]);
    }
}

__global__ __launch_bounds__(256) void conv_kernel(const float* __restrict__ in,
                                                   unsigned short* __restrict__ out,
                                                   long n4) {
    long i = (long)blockIdx.x * 256 + threadIdx.x;
    if (i < n4) {
        float4 v = ((const float4*)in)[i];
        ushort4 o;
        o.x = f2bf_bits(v.x); o.y = f2bf_bits(v.y);
        o.z = f2bf_bits(v.z); o.w = f2bf_bits(v.w);
        ((ushort4*)out)[i] = o;
    }
}

// ---------------------------------------------------------------------------
// bf16 MFMA GEMM, m97 structure (128x128, BK=32, 4 waves). OUTMODE as before.
template <int ACT, int RES, int OUTMODE>
__global__ __launch_bounds__(256) void gemm_mfma(const unsigned short* __restrict__ A,
                                                 const unsigned short* __restrict__ Bt,
                                                 const float* __restrict__ bias,
                                                 const float* res,
                                                 void* Cout, int M, int N, int K,
                                                 const float* biasK, const float* biasV,
                                                 unsigned short* kout, unsigned short* vtout) {
    __shared__ unsigned short As[128 * 32];
    __shared__ unsigned short Bs[128 * 32];
    const int tid = threadIdx.x;
    const int bm = blockIdx.y * 128, bn = blockIdx.x * 128;
    const int lane = tid & 63;
    const int wave = tid >> 6;
    const int wm = (wave >> 1) * 64, wn = (wave & 1) * 64;

    f4v acc[4][4];
    #pragma unroll
    for (int i = 0; i < 4; i++)
        #pragma unroll
        for (int j = 0; j < 4; j++)
            acc[i][j] = (f4v){0.f, 0.f, 0.f, 0.f};

    const int arow = tid >> 2;
    const int acol = (tid & 3) * 8;
    const unsigned short* gA0 = A  + (size_t)(bm + arow) * K + acol;
    const unsigned short* gA1 = gA0 + (size_t)64 * K;
    const unsigned short* gB0 = Bt + (size_t)(bn + arow) * K + acol;
    const unsigned short* gB1 = gB0 + (size_t)64 * K;
    char* lA0 = (char*)As + tid * 16;
    char* lA1 = lA0 + 4096;
    char* lB0 = (char*)Bs + tid * 16;
    char* lB1 = lB0 + 4096;

    const int fr = lane & 15;
    const int fk = (lane >> 4) * 8;

    for (int k0 = 0; k0 < K; k0 += 32) {
        gl_lds16(gA0 + k0, lA0);
        gl_lds16(gA1 + k0, lA1);
        gl_lds16(gB0 + k0, lB0);
        gl_lds16(gB1 + k0, lB1);
        __syncthreads();
        s8v af[4], bf[4];
        #pragma unroll
        for (int i = 0; i < 4; i++)
            af[i] = *(const s8v*)(As + (wm + i * 16 + fr) * 32 + fk);
        #pragma unroll
        for (int j = 0; j < 4; j++)
            bf[j] = *(const s8v*)(Bs + (wn + j * 16 + fr) * 32 + fk);
        #pragma unroll
        for (int i = 0; i < 4; i++)
            #pragma unroll
            for (int j = 0; j < 4; j++)
                acc[i][j] = __builtin_amdgcn_mfma_f32_16x16x32_bf16(af[i], bf[j], acc[i][j], 0, 0, 0);
        __syncthreads();
    }

    const int r0 = bm + wm + (lane >> 4) * 4;
    const int c0 = bn + wn + fr;
    #pragma unroll
    for (int i = 0; i < 4; i++) {
        const int rb = r0 + i * 16;
        #pragma unroll
        for (int j = 0; j < 4; j++) {
            const int c = c0 + j * 16;
            if (OUTMODE == 3) {
                const int seg = (c >= 1536) ? 2 : (c >= 768 ? 1 : 0);
                const int cc = c - seg * 768;
                const float bb = (seg == 0 ? bias[cc] : seg == 1 ? biasK[cc] : biasV[cc]);
                if (seg < 2) {
                    unsigned short* dst = (seg == 0 ? (unsigned short*)Cout : kout);
                    #pragma unroll
                    for (int q = 0; q < 4; q++)
                        dst[(size_t)(rb + q) * DD + cc] = f2bf_bits(acc[i][j][q] + bb);
                } else {
                    const int b_ = rb / SS, s_ = rb % SS;
                    const int h_ = cc >> 6, dd = cc & 63;
                    ushort4 pk;
                    pk.x = f2bf_bits(acc[i][j][0] + bb);
                    pk.y = f2bf_bits(acc[i][j][1] + bb);
                    pk.z = f2bf_bits(acc[i][j][2] + bb);
                    pk.w = f2bf_bits(acc[i][j][3] + bb);
                    *(ushort4*)(vtout + ((size_t)(b_ * HH + h_) * DK + dd) * SS + s_) = pk;
                }
            } else {
                const float bv = bias ? bias[c] : 0.f;
                #pragma unroll
                for (int q = 0; q < 4; q++) {
                    const int r = rb + q;
                    float v = acc[i][j][q] + bv;
                    if (ACT) v = 0.5f * v * (1.0f + erff(v * 0.70710678118654752f));
                    if (RES) v += res[(size_t)r * N + c];
                    if (OUTMODE == 1) ((unsigned short*)Cout)[(size_t)r * N + c] = f2bf_bits(v);
                    else              ((float*)Cout)[(size_t)r * N + c] = v;
                }
            }
        }
    }
}

// ---------------------------------------------------------------------------
// Head GEMM: 256x128 tile, BK=32, 512 threads (8 waves 4x2), fp32 NT stores,
// bijective XCD swizzle. C[M,N] = A[M,K] @ Bt[N,K]^T, no bias.
__global__ __launch_bounds__(512) void gemm_head(const unsigned short* __restrict__ A,
                                                 const unsigned short* __restrict__ Bt,
                                                 float* __restrict__ C,
                                                 int M, int N, int K) {
    __shared__ unsigned short As[256 * 32];
    __shared__ unsigned short Bs[128 * 32];
    const int tid = threadIdx.x;

    // XCD-aware bijective swizzle of flat block id (nwg divisible by 8)
    const int nwg = gridDim.x * gridDim.y;
    const int bid = blockIdx.y * gridDim.x + blockIdx.x;
    const int cpx = nwg >> 3;
    const int swz = (bid & 7) * cpx + (bid >> 3);
    const int bx = swz % gridDim.x;
    const int by = swz / gridDim.x;
    const int bm = by * 256, bn = bx * 128;

    const int lane = tid & 63;
    const int wave = tid >> 6;
    const int wm = (wave >> 1) * 64;      // 0,64,128,192
    const int wn = (wave & 1) * 64;       // 0,64

    f4v acc[4][4];
    #pragma unroll
    for (int i = 0; i < 4; i++)
        #pragma unroll
        for (int j = 0; j < 4; j++)
            acc[i][j] = (f4v){0.f, 0.f, 0.f, 0.f};

    const int arow = tid >> 2;            // 0..127
    const int acol = (tid & 3) * 8;
    const unsigned short* gA0 = A  + (size_t)(bm + arow) * K + acol;
    const unsigned short* gA1 = gA0 + (size_t)128 * K;
    const unsigned short* gB  = Bt + (size_t)(bn + arow) * K + acol;
    char* lA0 = (char*)As + tid * 16;     // rows 0..127
    char* lA1 = lA0 + 8192;               // rows 128..255
    char* lB  = (char*)Bs + tid * 16;

    const int fr = lane & 15;
    const int fk = (lane >> 4) * 8;

    for (int k0 = 0; k0 < K; k0 += 32) {
        gl_lds16(gA0 + k0, lA0);
        gl_lds16(gA1 + k0, lA1);
        gl_lds16(gB + k0, lB);
        __syncthreads();
        s8v af[4], bf[4];
        #pragma unroll
        for (int i = 0; i < 4; i++)
            af[i] = *(const s8v*)(As + (wm + i * 16 + fr) * 32 + fk);
        #pragma unroll
        for (int j = 0; j < 4; j++)
            bf[j] = *(const s8v*)(Bs + (wn + j * 16 + fr) * 32 + fk);
        #pragma unroll
        for (int i = 0; i < 4; i++)
            #pragma unroll
            for (int j = 0; j < 4; j++)
                acc[i][j] = __builtin_amdgcn_mfma_f32_16x16x32_bf16(af[i], bf[j], acc[i][j], 0, 0, 0);
        __syncthreads();
    }

    const int r0 = bm + wm + (lane >> 4) * 4;
    const int c0 = bn + wn + fr;
    #pragma unroll
    for (int i = 0; i < 4; i++) {
        #pragma unroll
        for (int j = 0; j < 4; j++) {
            const int c = c0 + j * 16;
            #pragma unroll
            for (int q = 0; q < 4; q++) {
                const int r = r0 + i * 16 + q;
                __builtin_nontemporal_store(acc[i][j][q], &C[(size_t)r * N + c]);
            }
        }
    }
}

// ---------------------------------------------------------------------------
// Flash attention: block = (qtile 64 rows, b*H), 4 waves x 16 q-rows, KVBLK=128.
// q,k: bf16 [M,D]; vt: bf16 [B,H,DK,S]; o: bf16 [M,D].
__global__ __launch_bounds__(256) void fattn_kernel(const unsigned short* __restrict__ qb,
                                                    const unsigned short* __restrict__ kb,
                                                    const unsigned short* __restrict__ vt,
                                                    unsigned short* __restrict__ o) {
    __shared__ unsigned short Ks[128 * 64];   // [key][dk], rows 128B, XOR-swizzled
    __shared__ unsigned short Vs[64 * 128];   // [dk][key], rows 256B, XOR-swizzled
    __shared__ unsigned short Ps[4][16 * 128]; // per-wave P, rows 256B, XOR-swizzled

    const int qt = (int)gridDim.x - 1 - (int)blockIdx.x;   // heavy tiles first
    const int bh = blockIdx.y;
    const int b = bh / HH, h = bh % HH;
    const int tid = threadIdx.x;
    const int lane = tid & 63;
    const int w = tid >> 6;
    const int fr = lane & 15;
    const int g  = lane >> 4;

    // K staging: dest chunk (tid&7) of row i*32+(tid>>3); source col pre-swizzled
    const int krow_ = tid >> 3;                          // 0..31
    const int kcol = (((tid & 7) ^ (krow_ & 7)) * 8);
    // V staging: dest chunk (tid&15) of row i*16+(tid>>4)
    const int vrow_ = tid >> 4;                          // 0..15
    const int vcol = (((tid & 15) ^ (vrow_ & 7)) * 8);

    const int q0w = qt * 64 + w * 16;
    s8v qf[2];
    {
        const unsigned short* qrow = qb + (size_t)(b * SS + q0w + fr) * DD + h * DK + g * 8;
        qf[0] = *(const s8v*)(qrow);
        qf[1] = *(const s8v*)(qrow + 32);
    }

    f4v ofr[4];
    #pragma unroll
    for (int dj = 0; dj < 4; dj++) ofr[dj] = (f4v){0.f, 0.f, 0.f, 0.f};
    float mrow[4] = {-1e30f, -1e30f, -1e30f, -1e30f};
    float lrow[4] = {0.f, 0.f, 0.f, 0.f};

    unsigned short* Pw = &Ps[w][0];
    const int ktiles = qt / 2 + 1;

    for (int t = 0; t < ktiles; ++t) {
        const int k0 = t * 128;
        #pragma unroll
        for (int i = 0; i < 4; i++) {
            const int r = i * 32 + krow_;      // key row 0..127; r&7 == krow_&7
            gl_lds16(kb + (size_t)(b * SS + k0 + r) * DD + h * DK + kcol,
                     (char*)Ks + i * 4096 + tid * 16);
        }
        #pragma unroll
        for (int i = 0; i < 4; i++) {
            const int d = i * 16 + vrow_;      // dk row 0..63; d&7 == vrow_&7
            gl_lds16(vt + ((size_t)bh * DK + d) * SS + k0 + vcol,
                     (char*)Vs + i * 4096 + tid * 16);
        }
        __syncthreads();

        // QK^T -> S frags [16q x 128k]
        const bool diag = (t == ktiles - 1);
        float p[8][4];
        #pragma unroll
        for (int j = 0; j < 8; j++) {
            const char* kbase = (const char*)Ks + (j * 16 + fr) * 128;  // row&7 == fr&7
            s8v b0 = *(const s8v*)(kbase + ((g * 16)      ^ ((fr & 7) << 4)));
            s8v b1 = *(const s8v*)(kbase + ((64 + g * 16) ^ ((fr & 7) << 4)));
            f4v a = (f4v){0.f, 0.f, 0.f, 0.f};
            a = __builtin_amdgcn_mfma_f32_16x16x32_bf16(qf[0], b0, a, 0, 0, 0);
            a = __builtin_amdgcn_mfma_f32_16x16x32_bf16(qf[1], b1, a, 0, 0, 0);
            #pragma unroll
            for (int pq = 0; pq < 4; pq++) {
                float sv = a[pq] * 0.125f;
                if (diag && (k0 + j * 16 + fr > q0w + g * 4 + pq)) sv = -1e30f;
                p[j][pq] = sv;
            }
        }

        // row max (16-lane group reduce)
        float rmx[4];
        #pragma unroll
        for (int pq = 0; pq < 4; pq++) {
            float v0 = fmaxf(fmaxf(p[0][pq], p[1][pq]), fmaxf(p[2][pq], p[3][pq]));
            float v1 = fmaxf(fmaxf(p[4][pq], p[5][pq]), fmaxf(p[6][pq], p[7][pq]));
            rmx[pq] = fmaxf(v0, v1);
        }
        #pragma unroll
        for (int off = 1; off < 16; off <<= 1)
            #pragma unroll
            for (int pq = 0; pq < 4; pq++)
                rmx[pq] = fmaxf(rmx[pq], __shfl_xor(rmx[pq], off));

        float mnew[4], scf[4], rsum[4];
        #pragma unroll
        for (int pq = 0; pq < 4; pq++) {
            mnew[pq] = fmaxf(mrow[pq], rmx[pq]);
            scf[pq]  = __expf(mrow[pq] - mnew[pq]);
            rsum[pq] = 0.f;
        }
        #pragma unroll
        for (int j = 0; j < 8; j++)
            #pragma unroll
            for (int pq = 0; pq < 4; pq++) {
                float e = __expf(p[j][pq] - mnew[pq]);
                p[j][pq] = e;
                rsum[pq] += e;
            }
        #pragma unroll
        for (int off = 1; off < 16; off <<= 1)
            #pragma unroll
            for (int pq = 0; pq < 4; pq++)
                rsum[pq] += __shfl_xor(rsum[pq], off);
        #pragma unroll
        for (int pq = 0; pq < 4; pq++) {
            lrow[pq] = lrow[pq] * scf[pq] + rsum[pq];
            mrow[pq] = mnew[pq];
        }
        #pragma unroll
        for (int dj = 0; dj < 4; dj++)
            #pragma unroll
            for (int pq = 0; pq < 4; pq++)
                ofr[dj][pq] *= scf[pq];

        // P -> LDS (bf16, swizzled), wave-private
        #pragma unroll
        for (int j = 0; j < 8; j++)
            #pragma unroll
            for (int pq = 0; pq < 4; pq++) {
                const int r = g * 4 + pq;
                *(unsigned short*)((char*)Pw + r * 256 +
                                   (((j * 16 + fr) * 2) ^ ((r & 7) << 4))) = f2bf_bits(p[j][pq]);
            }

        // PV: O += P[16x128] @ Vs[64d x 128k] (B operand rows = d)
        s8v pa[4];
        #pragma unroll
        for (int ks = 0; ks < 4; ks++)
            pa[ks] = *(const s8v*)((const char*)Pw + fr * 256 +
                                   ((ks * 64 + g * 16) ^ ((fr & 7) << 4)));
        #pragma unroll
        for (int dj = 0; dj < 4; dj++) {
            const char* vbase = (const char*)Vs + (dj * 16 + fr) * 256;  // row&7 == fr&7
            #pragma unroll
            for (int ks = 0; ks < 4; ks++) {
                s8v vv = *(const s8v*)(vbase + ((ks * 64 + g * 16) ^ ((fr & 7) << 4)));
                ofr[dj] = __builtin_amdgcn_mfma_f32_16x16x32_bf16(pa[ks], vv, ofr[dj], 0, 0, 0);
            }
        }
        __syncthreads();
    }

    // epilogue
    #pragma unroll
    for (int pq = 0; pq < 4; pq++) {
        const float inv = 1.0f / lrow[pq];
        const int row_abs = q0w + g * 4 + pq;
        #pragma unroll
        for (int dj = 0; dj < 4; dj++)
            o[(size_t)(b * SS + row_abs) * DD + h * DK + dj * 16 + fr] =
                f2bf_bits(ofr[dj][pq] * inv);
    }
}

// ---------------------------------------------------------------------------
extern "C" void kernel_launch(void* const* d_in, const int* in_sizes, int n_in,
                              void* d_out, int out_size, void* d_ws, size_t ws_size,
                              hipStream_t stream) {
    const int*   tokens = (const int*)d_in[0];
    const float* emb    = (const float*)d_in[1];
    const float* Wq     = (const float*)d_in[2];
    const float* bq     = (const float*)d_in[3];
    const float* Wk     = (const float*)d_in[4];
    const float* bk     = (const float*)d_in[5];
    const float* Wv     = (const float*)d_in[6];
    const float* bv     = (const float*)d_in[7];
    const float* Wo     = (const float*)d_in[8];
    const float* bo     = (const float*)d_in[9];
    const float* W1     = (const float*)d_in[10];
    const float* b1     = (const float*)d_in[11];
    const float* W2     = (const float*)d_in[12];
    const float* b2     = (const float*)d_in[13];
    const float* ln1_g  = (const float*)d_in[14];
    const float* ln1_b  = (const float*)d_in[15];
    const float* ln2_g  = (const float*)d_in[16];
    const float* ln2_b  = (const float*)d_in[17];
    const float* lnf_g  = (const float*)d_in[18];
    const float* lnf_b  = (const float*)d_in[19];
    const float* headW  = (const float*)d_in[20];
    float* out = (float*)d_out;
    (void)in_sizes; (void)n_in; (void)out_size; (void)ws_size;

    const size_t MD  = (size_t)MM * DD;
    const size_t MF  = (size_t)MM * FF;
    const size_t DxD = (size_t)DD * DD;
    const size_t DxF = (size_t)DD * FF;
    const size_t HWs = (size_t)VV * DD;

    char* p = (char*)d_ws;
    float*          x     = (float*)p;          p += MD * 4;
    unsigned short* qb    = (unsigned short*)p; p += MD * 2;
    unsigned short* kbuf  = (unsigned short*)p; p += MD * 2;
    unsigned short* vtb   = (unsigned short*)p; p += MD * 2;
    unsigned short* ao    = (unsigned short*)p; p += MD * 2;
    unsigned short* h     = (unsigned short*)p; p += MD * 2;
    unsigned short* mid   = (unsigned short*)p; p += MF * 2;
    unsigned short* wqkvT = (unsigned short*)p; p += 3 * DxD * 2;
    unsigned short* woT   = (unsigned short*)p; p += DxD * 2;
    unsigned short* w1T   = (unsigned short*)p; p += DxF * 2;
    unsigned short* w2T   = (unsigned short*)p; p += DxF * 2;
    unsigned short* hw    = (unsigned short*)p; p += HWs * 2;

    embed_kernel<<<MM, 256, 0, stream>>>(tokens, emb, x);
    conv_kernel<<<(int)((HWs / 4 + 255) / 256), 256, 0, stream>>>(headW, hw, (long)(HWs / 4));

    const dim3 gQKV(2304 / 128, MM / 128);
    const dim3 gD(DD / 128, MM / 128);
    const dim3 gF(FF / 128, MM / 128);
    const dim3 gHead(VV / 128, MM / 256);    // (250, 16)
    const dim3 gA(SS / 64, BB * HH);

    for (int l = 0; l < LL; l++) {
        prep_kernel<<<1728, 256, 0, stream>>>(Wq + l * DxD, Wk + l * DxD, Wv + l * DxD,
                                              Wo + l * DxD, W1 + l * DxF, W2 + l * DxF,
                                              wqkvT, woT, w1T, w2T);
        ln_kernel<1><<<MM, 256, 0, stream>>>(x, ln1_g + l * DD, ln1_b + l * DD, h);
        gemm_mfma<0, 0, 3><<<gQKV, 256, 0, stream>>>(h, wqkvT, bq + l * DD, nullptr, qb,
                                                     MM, 2304, DD,
                                                     bk + l * DD, bv + l * DD, kbuf, vtb);
        fattn_kernel<<<gA, 256, 0, stream>>>(qb, kbuf, vtb, ao);
        gemm_mfma<0, 1, 0><<<gD, 256, 0, stream>>>(ao, woT, bo + l * DD, x, x, MM, DD, DD,
                                                   nullptr, nullptr, nullptr, nullptr);
        ln_kernel<1><<<MM, 256, 0, stream>>>(x, ln2_g + l * DD, ln2_b + l * DD, h);
        gemm_mfma<1, 0, 1><<<gF, 256, 0, stream>>>(h, w1T, b1 + l * FF, nullptr, mid,
                                                   MM, FF, DD, nullptr, nullptr, nullptr, nullptr);
        gemm_mfma<0, 1, 0><<<gD, 256, 0, stream>>>(mid, w2T, b2 + l * DD, x, x, MM, DD, FF,
                                                   nullptr, nullptr, nullptr, nullptr);
    }

    ln_kernel<1><<<MM, 256, 0, stream>>>(x, lnf_g, lnf_b, h);
    gemm_head<<<gHead, 512, 0, stream>>>(h, hw, out, MM, VV, DD);
}